// Round 20
// baseline (476.331 us; speedup 1.0000x reference)
//
#include <hip/hip_runtime.h>
#include <hip/hip_bf16.h>
#include <math.h>

// DiT flow: B=64,S=32 -> M=2048 tokens, D=512, NH=8, HD=64, FF=2048, L=6, IN=9216.
// Device buffers are FLOAT32. Compute: bf16 MFMA, f32 accumulation; weights
// pre-converted to bf16 in ws each call (deterministic).
// NOTE (r16): no runtime-indexed register staging arrays (rule #20 scratch).
// r20: mega-kernel = in-proj GEMM (A,W both f32, converted in-register) +
//      convert of all other tensors + rtab/inp_b, zero prologue.

typedef __attribute__((ext_vector_type(8))) short bf16x8;
typedef __attribute__((ext_vector_type(4))) short bf16x4;
typedef __attribute__((ext_vector_type(8))) float f32x8;
typedef __attribute__((ext_vector_type(4))) float f32x4;

#define LN_EPS 1e-5f

__device__ inline float bf2f(__hip_bfloat16 v) { return __bfloat162float(v); }
__device__ inline __hip_bfloat16 f2bf(float f) { return __float2bfloat16(f); }

__device__ __forceinline__ void sync_lds() {   // no vmem drain — reg-staged paths
    asm volatile("s_waitcnt lgkmcnt(0)" ::: "memory");
    __builtin_amdgcn_s_barrier();
    asm volatile("" ::: "memory");
}

// ---------------------------------------------------------------------------
struct CvtSeg { const float* src; __hip_bfloat16* dst; };
struct CvtArgs14 { CvtSeg seg[14]; long cum[15]; };

// ---------------------------------------------------------------------------
// Mega-kernel:
//   blocks [0,512)    : in-proj GEMM, 64x256 tile, z=8, A (x) and B (inp_w)
//                       both read as f32 and converted in-register; fully
//                       reg-staged, lgkm-only sync (no vmem drain in loop).
//   blocks [512,2560) : grid-stride convert of 14 tensors; block 512 also
//                       fills the rope table and converts inp_b.
// ---------------------------------------------------------------------------
__global__ __launch_bounds__(256) void inproj_conv(
    const float* __restrict__ Xf,              // [2048,9216] f32
    const float* __restrict__ Wf,              // [512,9216] f32 (inp_w)
    float* __restrict__ part,                  // [8][2048][512] f32 partials
    CvtArgs14 ca, long total8,
    const float* __restrict__ inpb_f, __hip_bfloat16* __restrict__ inpb_b,
    float* __restrict__ rtab)
{
    __shared__ __align__(16) __hip_bfloat16 sA[64 * 64];
    __shared__ __align__(16) __hip_bfloat16 sB[256 * 64];

    const int tid = threadIdx.x;

    if (blockIdx.x >= 512) {
        // ---- convert role ----
        if (blockIdx.x == 512) {
            // rope table: tab[s*64+p*2]=cos, +1=sin
#pragma unroll
            for (int it = 0; it < 4; ++it) {
                const int t = it * 256 + tid;
                const int s = t >> 5, p = t & 31;
                const float theta = powf(10000.f, -(float)p / 32.f);
                float sn, cs;
                sincosf((float)s * theta, &sn, &cs);
                rtab[t * 2] = cs;
                rtab[t * 2 + 1] = sn;
            }
            if (tid < 64) {   // inp_b: 512 elems = 64 chunks
                const long o = tid;
                const f32x8 x = *((const f32x8*)inpb_f + o);
                union { bf16x8 v; __hip_bfloat16 b[8]; } u;
#pragma unroll
                for (int t = 0; t < 8; ++t) u.b[t] = f2bf(x[t]);
                *((bf16x8*)inpb_b + o) = u.v;
            }
        }
        const long st = 2048L * 256;
        for (long i = (long)(blockIdx.x - 512) * 256 + tid; i < total8; i += 2 * st) {
            int s1 = 0;
            while (i >= ca.cum[s1 + 1]) ++s1;
            const long o1 = i - ca.cum[s1];
            const f32x8 x1 = *((const f32x8*)ca.seg[s1].src + o1);
            const long j = i + st;
            if (j < total8) {
                int s2 = s1;
                while (j >= ca.cum[s2 + 1]) ++s2;
                const long o2 = j - ca.cum[s2];
                const f32x8 x2 = *((const f32x8*)ca.seg[s2].src + o2);
                union { bf16x8 v; __hip_bfloat16 b[8]; } u1, u2;
#pragma unroll
                for (int t = 0; t < 8; ++t) { u1.b[t] = f2bf(x1[t]); u2.b[t] = f2bf(x2[t]); }
                *((bf16x8*)ca.seg[s1].dst + o1) = u1.v;
                *((bf16x8*)ca.seg[s2].dst + o2) = u2.v;
            } else {
                union { bf16x8 v; __hip_bfloat16 b[8]; } u1;
#pragma unroll
                for (int t = 0; t < 8; ++t) u1.b[t] = f2bf(x1[t]);
                *((bf16x8*)ca.seg[s1].dst + o1) = u1.v;
            }
        }
        return;
    }

    // ---- in-proj GEMM role ----
    const int lane = tid & 63, wave = tid >> 6;
    const int wr = wave >> 1, wc = wave & 1;
    const int lr = lane & 15, lk = lane >> 4;

    const int bid = blockIdx.x;
    const int xcd = bid & 7, loc = bid >> 3;       // A-panel-per-XCD grouping
    const int bn = loc & 1;                        // nbn = 2
    const int gid = xcd * 32 + (loc >> 1);         // per = (512/8)/2 = 32
    const int bm = gid & 31;
    const int zz = gid >> 5;                       // zz == xcd
    const int kbeg = zz * 1152, kend = kbeg + 1152;

    const float* Ab = Xf + (long)bm * 64 * 9216;
    const float* Wb = Wf + (long)bn * 256 * 9216;

    f32x4 acc[2][8];
#pragma unroll
    for (int i = 0; i < 2; ++i)
#pragma unroll
        for (int j = 0; j < 8; ++j) acc[i][j] = (f32x4){0.f, 0.f, 0.f, 0.f};

    f32x8 aregf[2];
    f32x8 bregf[8];

    auto issueA = [&](int k0) {
#pragma unroll
        for (int c = 0; c < 2; ++c) {
            const int ch = tid + c * 256, row = ch >> 3, co = ch & 7;
            aregf[c] = *(const f32x8*)&Ab[(long)row * 9216 + k0 + co * 8];
        }
#pragma unroll
        for (int c = 0; c < 8; ++c) {
            const int ch = tid + c * 256, row = ch >> 3, co = ch & 7;
            bregf[c] = *(const f32x8*)&Wb[(long)row * 9216 + k0 + co * 8];
        }
    };
    auto writeA = [&]() {
#pragma unroll
        for (int c = 0; c < 2; ++c) {
            const int ch = tid + c * 256, row = ch >> 3, co = ch & 7;
            union { bf16x8 v; __hip_bfloat16 b[8]; } t;
#pragma unroll
            for (int j = 0; j < 8; ++j) t.b[j] = f2bf(aregf[c][j]);
            *(bf16x8*)((char*)sA + row * 128 + ((co ^ (row & 7)) << 4)) = t.v;
        }
#pragma unroll
        for (int c = 0; c < 8; ++c) {
            const int ch = tid + c * 256, row = ch >> 3, co = ch & 7;
            union { bf16x8 v; __hip_bfloat16 b[8]; } t;
#pragma unroll
            for (int j = 0; j < 8; ++j) t.b[j] = f2bf(bregf[c][j]);
            *(bf16x8*)((char*)sB + row * 128 + ((co ^ (row & 7)) << 4)) = t.v;
        }
    };
    auto compute = [&]() {
        bf16x8 af[2][2], bfr[2][8];
#pragma unroll
        for (int ks = 0; ks < 2; ++ks) {
#pragma unroll
            for (int i = 0; i < 2; ++i) {
                const int row = wr * 32 + i * 16 + lr;
                const int co = ks * 4 + lk;
                af[ks][i] = *(const bf16x8*)((const char*)sA + row * 128 +
                                             ((co ^ (row & 7)) << 4));
            }
#pragma unroll
            for (int j = 0; j < 8; ++j) {
                const int row = wc * 128 + j * 16 + lr;
                const int co = ks * 4 + lk;
                bfr[ks][j] = *(const bf16x8*)((const char*)sB + row * 128 +
                                              ((co ^ (row & 7)) << 4));
            }
        }
#pragma unroll
        for (int ks = 0; ks < 2; ++ks)
#pragma unroll
            for (int i = 0; i < 2; ++i)
#pragma unroll
                for (int j = 0; j < 8; ++j)
                    acc[i][j] = __builtin_amdgcn_mfma_f32_16x16x32_bf16(
                        af[ks][i], bfr[ks][j], acc[i][j], 0, 0, 0);
    };

    issueA(kbeg);
    for (int k0 = kbeg; k0 < kend; k0 += 64) {
        if (k0 > kbeg) __builtin_amdgcn_s_barrier();
        writeA();
        sync_lds();
        if (k0 + 64 < kend) issueA(k0 + 64);
        compute();
    }

    float* Cp = part + (long)zz * 2048 * 512;
    const int row0 = bm * 64 + wr * 32;
    const int col0 = bn * 256 + wc * 128;
#pragma unroll
    for (int i = 0; i < 2; ++i)
#pragma unroll
        for (int j = 0; j < 8; ++j) {
            const int col = col0 + j * 16 + lr;
#pragma unroll
            for (int r = 0; r < 4; ++r)
                Cp[(long)(row0 + i * 16 + lk * 4 + r) * 512 + col] = acc[i][j][r];
        }
}

// ---------------------------------------------------------------------------
// GEMM: C[M,N] = A[M,K] @ W[N,K]^T (+bias, +gelu). Tile BM x BN, BK=64,
// 4 waves 2x2 (per-wave (BM/2)x(BN/2)). XOR-swizzled LDS rows (involution).
// A bf16 (rope for bn < bn_split) + B bf16 reg-staged, lgkm-only sync.
// OUT: 0 = bf16 +bias(+EPI gelu); 1 = f32 split-K partial; 2 = f32 +bias.
// ---------------------------------------------------------------------------
template<int BM, int BN, int EPI, int OUT>
__global__ __launch_bounds__(256) void gemm_bt(
    const void* __restrict__ Araw, int bn_split,
    const float* __restrict__ rtab,
    const __hip_bfloat16* __restrict__ W,
    const __hip_bfloat16* __restrict__ bias,
    void* __restrict__ Cv,
    int M, int N, int Ktot, int KC)
{
    constexpr int FM = BM / 32, FN = BN / 32;
    constexpr int CPT_A = BM / 32, CPT_B = BN / 32;
    __shared__ __align__(16) __hip_bfloat16 sA[BM * 64];
    __shared__ __align__(16) __hip_bfloat16 sB[BN * 64];

    const int tid = threadIdx.x, lane = tid & 63, wave = tid >> 6;
    const int wr = wave >> 1, wc = wave & 1;
    const int lr = lane & 15, lk = lane >> 4;

    const int nbm = gridDim.x, nbn = gridDim.y;
    const int nwg = nbm * nbn;
    const int orig = blockIdx.y * nbm + blockIdx.x;
    const int q8 = nwg >> 3, r8 = nwg & 7;
    const int xcd = orig & 7, loc = orig >> 3;
    const int f = (xcd < r8 ? xcd * (q8 + 1) : r8 * (q8 + 1) + (xcd - r8) * q8) + loc;
    const int bm = f % nbm, bn = f / nbm;
    const int zz = blockIdx.z;
    const int kbeg = zz * KC, kend = kbeg + KC;
    const bool dorot = (bn < bn_split);

    const __hip_bfloat16* Ab = (const __hip_bfloat16*)Araw + (long)bm * BM * Ktot;
    const __hip_bfloat16* Wb = W + (long)bn * BN * Ktot;

    f32x4 acc[FM][FN];
#pragma unroll
    for (int i = 0; i < FM; ++i)
#pragma unroll
        for (int j = 0; j < FN; ++j) acc[i][j] = (f32x4){0.f, 0.f, 0.f, 0.f};

    bf16x8 aregb[CPT_A];
    f32x8  csreg[CPT_A];
    bf16x8 bregb[CPT_B];

    auto issueA = [&](int k0) {
#pragma unroll
        for (int c = 0; c < CPT_A; ++c) {
            const int ch = tid + c * 256, row = ch >> 3, co = ch & 7;
            aregb[c] = *(const bf16x8*)&Ab[(long)row * Ktot + k0 + co * 8];
            if (dorot)
                csreg[c] = *(const f32x8*)&rtab[((bm * BM + row) & 31) * 64 + co * 8];
        }
#pragma unroll
        for (int c = 0; c < CPT_B; ++c) {
            const int ch = tid + c * 256, row = ch >> 3, co = ch & 7;
            bregb[c] = *(const bf16x8*)&Wb[(long)row * Ktot + k0 + co * 8];
        }
    };
    auto writeA = [&]() {
#pragma unroll
        for (int c = 0; c < CPT_A; ++c) {
            const int ch = tid + c * 256, row = ch >> 3, co = ch & 7;
            union { bf16x8 v; __hip_bfloat16 b[8]; } t;
            t.v = aregb[c];
            if (dorot) {
#pragma unroll
                for (int qd = 0; qd < 4; ++qd) {
                    const float c_ = csreg[c][qd * 2], sn = csreg[c][qd * 2 + 1];
                    const float x0 = bf2f(t.b[2 * qd]);
                    const float x1 = bf2f(t.b[2 * qd + 1]);
                    t.b[2 * qd]     = f2bf(x0 * c_ - x1 * sn);
                    t.b[2 * qd + 1] = f2bf(x1 * c_ + x0 * sn);
                }
            }
            *(bf16x8*)((char*)sA + row * 128 + ((co ^ (row & 7)) << 4)) = t.v;
        }
#pragma unroll
        for (int c = 0; c < CPT_B; ++c) {
            const int ch = tid + c * 256, row = ch >> 3, co = ch & 7;
            *(bf16x8*)((char*)sB + row * 128 + ((co ^ (row & 7)) << 4)) = bregb[c];
        }
    };
    auto compute = [&]() {
        bf16x8 af[2][FM], bfr[2][FN];
#pragma unroll
        for (int ks = 0; ks < 2; ++ks) {
#pragma unroll
            for (int i = 0; i < FM; ++i) {
                const int row = wr * (BM / 2) + i * 16 + lr;
                const int co = ks * 4 + lk;
                af[ks][i] = *(const bf16x8*)((const char*)sA + row * 128 +
                                             ((co ^ (row & 7)) << 4));
            }
#pragma unroll
            for (int j = 0; j < FN; ++j) {
                const int row = wc * (BN / 2) + j * 16 + lr;
                const int co = ks * 4 + lk;
                bfr[ks][j] = *(const bf16x8*)((const char*)sB + row * 128 +
                                              ((co ^ (row & 7)) << 4));
            }
        }
#pragma unroll
        for (int ks = 0; ks < 2; ++ks)
#pragma unroll
            for (int i = 0; i < FM; ++i)
#pragma unroll
                for (int j = 0; j < FN; ++j)
                    acc[i][j] = __builtin_amdgcn_mfma_f32_16x16x32_bf16(
                        af[ks][i], bfr[ks][j], acc[i][j], 0, 0, 0);
    };

    issueA(kbeg);
    for (int k0 = kbeg; k0 < kend; k0 += 64) {
        if (k0 > kbeg) __builtin_amdgcn_s_barrier();
        writeA();
        sync_lds();
        if (k0 + 64 < kend) issueA(k0 + 64);
        compute();
    }

    const int row0 = bm * BM + wr * (BM / 2);
    const int col0 = bn * BN + wc * (BN / 2);
    if (OUT == 1) {
        float* Cp = (float*)Cv + (long)zz * M * N;
#pragma unroll
        for (int i = 0; i < FM; ++i)
#pragma unroll
            for (int j = 0; j < FN; ++j) {
                const int col = col0 + j * 16 + lr;
#pragma unroll
                for (int r = 0; r < 4; ++r)
                    Cp[(long)(row0 + i * 16 + lk * 4 + r) * N + col] = acc[i][j][r];
            }
    } else {
#pragma unroll
        for (int i = 0; i < FM; ++i)
#pragma unroll
            for (int j = 0; j < FN; ++j) {
                const int col = col0 + j * 16 + lr;
                const float bv = bf2f(bias[col]);
#pragma unroll
                for (int r = 0; r < 4; ++r) {
                    const int row = row0 + i * 16 + lk * 4 + r;
                    float v = acc[i][j][r] + bv;
                    if (EPI == 1) v = 0.5f * v * (1.0f + erff(v * 0.70710678118654752f));
                    const long idx = (long)row * N + col;
                    if (OUT == 2) ((float*)Cv)[idx] = v;
                    else          ((__hip_bfloat16*)Cv)[idx] = f2bf(v);
                }
            }
    }
}

// ---------------------------------------------------------------------------
template<int SK>
__global__ __launch_bounds__(256) void sk_reduce(
    const float* __restrict__ part, const __hip_bfloat16* __restrict__ bias,
    __hip_bfloat16* __restrict__ out)
{
    const long MN = 2048L * 512;
    const long i4 = ((long)blockIdx.x * 256 + threadIdx.x) * 4;
    f32x4 s = (f32x4){0.f, 0.f, 0.f, 0.f};
#pragma unroll
    for (int z = 0; z < SK; ++z) s += *(const f32x4*)&part[z * MN + i4];
    const int col = (int)(i4 & 511);
    union { bf16x4 v; __hip_bfloat16 b[4]; } o;
#pragma unroll
    for (int j = 0; j < 4; ++j) o.b[j] = f2bf(s[j] + bf2f(bias[col + j]));
    *(bf16x4*)&out[i4] = o.v;
}

// ---------------------------------------------------------------------------
template<int SK>
__global__ __launch_bounds__(256) void skred_add_ln(
    const float* __restrict__ part, const __hip_bfloat16* __restrict__ bias,
    const __hip_bfloat16* __restrict__ resid,
    const __hip_bfloat16* __restrict__ w, const __hip_bfloat16* __restrict__ b,
    __hip_bfloat16* __restrict__ out)
{
    const long MN = 2048L * 512;
    const int wave = threadIdx.x >> 6, lane = threadIdx.x & 63;
    const long row = (long)blockIdx.x * 4 + wave;
    const long base = row * 512 + lane * 8;

    f32x8 acc = *(const f32x8*)&part[base];
#pragma unroll
    for (int z = 1; z < SK; ++z) acc += *(const f32x8*)&part[z * MN + base];

    union { bf16x8 v; __hip_bfloat16 b[8]; } ur, uo;
    ur.v = *(const bf16x8*)&resid[base];

    float x[8];
    float s = 0.f, s2 = 0.f;
#pragma unroll
    for (int j = 0; j < 8; ++j) {
        const int col = lane * 8 + j;
        x[j] = acc[j] + bf2f(bias[col]) + bf2f(ur.b[j]);
        s += x[j];
        s2 += x[j] * x[j];
    }
#pragma unroll
    for (int off = 32; off; off >>= 1) {
        s  += __shfl_xor(s, off);
        s2 += __shfl_xor(s2, off);
    }
    const float mu = s * (1.f / 512.f);
    const float var = s2 * (1.f / 512.f) - mu * mu;
    const float rs = rsqrtf(var + LN_EPS);
#pragma unroll
    for (int j = 0; j < 8; ++j) {
        const int col = lane * 8 + j;
        uo.b[j] = f2bf((x[j] - mu) * rs * bf2f(w[col]) + bf2f(b[col]));
    }
    *(bf16x8*)&out[base] = uo.v;
}

// ---------------------------------------------------------------------------
// MFMA attention: one wave per (b,head); 4 waves/block, 128 blocks.
// ---------------------------------------------------------------------------
__global__ __launch_bounds__(256) void attn_mfma(
    const __hip_bfloat16* __restrict__ qkv, __hip_bfloat16* __restrict__ ctx)
{
    __shared__ __align__(16) __hip_bfloat16 sP[4][32 * 32];
    __shared__ __align__(16) __hip_bfloat16 sVT[4][64 * 32];

    const int wave = threadIdx.x >> 6, lane = threadIdx.x & 63;
    const int bh = blockIdx.x * 4 + wave;
    const int b = bh >> 3, head = bh & 7;
    const long tok0 = (long)b * 32;
    const int lr = lane & 15, lk = lane >> 4;

    const __hip_bfloat16* Qb = qkv + tok0 * 1536 + head * 64;
    const __hip_bfloat16* Kb = Qb + 512;
    const __hip_bfloat16* Vb = Qb + 1024;

#pragma unroll
    for (int t = 0; t < 4; ++t) {
        const int c = lane + t * 64, row = c >> 3, d0 = (c & 7) * 8;
        union { bf16x8 v; __hip_bfloat16 e[8]; } u;
        u.v = *(const bf16x8*)&Vb[(long)row * 1536 + d0];
#pragma unroll
        for (int e = 0; e < 8; ++e) sVT[wave][(d0 + e) * 32 + row] = u.e[e];
    }

    f32x4 sc[2][2];
#pragma unroll
    for (int i = 0; i < 2; ++i)
#pragma unroll
        for (int j = 0; j < 2; ++j) sc[i][j] = (f32x4){0.f, 0.f, 0.f, 0.f};
#pragma unroll
    for (int ks = 0; ks < 2; ++ks) {
        bf16x8 aq[2], bk[2];
#pragma unroll
        for (int i = 0; i < 2; ++i)
            aq[i] = *(const bf16x8*)&Qb[(long)(i * 16 + lr) * 1536 + ks * 32 + lk * 8];
#pragma unroll
        for (int j = 0; j < 2; ++j)
            bk[j] = *(const bf16x8*)&Kb[(long)(j * 16 + lr) * 1536 + ks * 32 + lk * 8];
#pragma unroll
        for (int i = 0; i < 2; ++i)
#pragma unroll
            for (int j = 0; j < 2; ++j)
                sc[i][j] = __builtin_amdgcn_mfma_f32_16x16x32_bf16(aq[i], bk[j], sc[i][j], 0, 0, 0);
    }

    float p[2][2][4], inv[2][4];
#pragma unroll
    for (int i = 0; i < 2; ++i) {
#pragma unroll
        for (int r = 0; r < 4; ++r) {
            const int row = i * 16 + lk * 4 + r;
            float m = -3.0e38f;
#pragma unroll
            for (int j = 0; j < 2; ++j) {
                const int col = j * 16 + lr;
                const float v = (col <= row) ? sc[i][j][r] * 0.125f : -3.0e38f;
                p[i][j][r] = v;
                m = fmaxf(m, v);
            }
#pragma unroll
            for (int off = 1; off < 16; off <<= 1)
                m = fmaxf(m, __shfl_xor(m, off));
            float l = 0.f;
#pragma unroll
            for (int j = 0; j < 2; ++j) {
                p[i][j][r] = expf(p[i][j][r] - m);
                l += p[i][j][r];
            }
#pragma unroll
            for (int off = 1; off < 16; off <<= 1)
                l += __shfl_xor(l, off);
            inv[i][r] = 1.f / l;
        }
    }

#pragma unroll
    for (int i = 0; i < 2; ++i)
#pragma unroll
        for (int j = 0; j < 2; ++j)
#pragma unroll
            for (int r = 0; r < 4; ++r)
                sP[wave][(i * 16 + lk * 4 + r) * 32 + j * 16 + lr] = f2bf(p[i][j][r]);

    bf16x8 pa[2], vb[4];
#pragma unroll
    for (int i = 0; i < 2; ++i)
        pa[i] = *(const bf16x8*)&sP[wave][(i * 16 + lr) * 32 + lk * 8];
#pragma unroll
    for (int j = 0; j < 4; ++j)
        vb[j] = *(const bf16x8*)&sVT[wave][(j * 16 + lr) * 32 + lk * 8];

    f32x4 o[2][4];
#pragma unroll
    for (int i = 0; i < 2; ++i)
#pragma unroll
        for (int j = 0; j < 4; ++j) {
            o[i][j] = (f32x4){0.f, 0.f, 0.f, 0.f};
            o[i][j] = __builtin_amdgcn_mfma_f32_16x16x32_bf16(pa[i], vb[j], o[i][j], 0, 0, 0);
        }

#pragma unroll
    for (int i = 0; i < 2; ++i)
#pragma unroll
        for (int j = 0; j < 4; ++j) {
            const int col = j * 16 + lr;
#pragma unroll
            for (int r = 0; r < 4; ++r) {
                const int row = i * 16 + lk * 4 + r;
                ctx[(tok0 + row) * 512 + head * 64 + col] = f2bf(o[i][j][r] * inv[i][r]);
            }
        }
}

// ---------------------------------------------------------------------------
extern "C" void kernel_launch(void* const* d_in, const int* in_sizes, int n_in,
                              void* d_out, int out_size, void* d_ws, size_t ws_size,
                              hipStream_t stream)
{
    const int M = 2048;
    __hip_bfloat16* wts = (__hip_bfloat16*)d_ws;

    const long O_INPROJ = 4718592;    // 4718592  (offset kept; inp_w slot unused)
    const long O_OUTW   = 9437184;    // 1572864
    const long O_FF1    = 11010048;   // 6291456
    const long O_FF2    = 17301504;   // 6291456
    const long O_OUTPW  = 23592960;   // 4718592
    const long O_INPB   = 28311552;   // 512
    const long O_INPROJB= 28312064;   // 9216
    const long O_OUTB   = 28321280;   // 3072
    const long O_LN1W   = 28324352;   // 3072
    const long O_LN1B   = 28327424;   // 3072
    const long O_LN2W   = 28330496;   // 3072
    const long O_LN2B   = 28333568;   // 3072
    const long O_FF1B   = 28336640;   // 12288
    const long O_FF2B   = 28348928;   // 3072
    const long O_OUTPB  = 28352000;   // 9216
    const long O_ACT    = 28361216;

    __hip_bfloat16* h   = wts + O_ACT;                   // [M,512]
    __hip_bfloat16* ht  = h   + (long)M * 512;
    __hip_bfloat16* qkv = ht  + (long)M * 512;           // [M,1536]
    __hip_bfloat16* ctx = qkv + (long)M * 1536;
    __hip_bfloat16* ffh = ctx + (long)M * 512;           // [M,2048]
    float* rtab = (float*)(ffh + (long)M * 2048);        // 8 KB
    float* skpart = (float*)((__hip_bfloat16*)rtab + 4096);  // 8 x 4.2 MB f32

    // 14 tensors converted by mega (in_proj, out_w, ff1, ff2, outp_w + biases/ln)
    const int  cidx[14] = {3, 5, 11, 13, 15, 4, 6, 7, 8, 9, 10, 12, 14, 16};
    const long coff[14] = {O_INPROJ, O_OUTW, O_FF1, O_FF2, O_OUTPW,
                           O_INPROJB, O_OUTB, O_LN1W, O_LN1B, O_LN2W,
                           O_LN2B, O_FF1B, O_FF2B, O_OUTPB};
    const long csz[14]  = {4718592, 1572864, 6291456, 6291456, 4718592,
                           9216, 3072, 3072, 3072, 3072, 3072, 12288, 3072, 9216};
    CvtArgs14 ca;
    long cum = 0;
    for (int s = 0; s < 14; ++s) {
        ca.seg[s].src = (const float*)d_in[cidx[s]];
        ca.seg[s].dst = wts + coff[s];
        ca.cum[s] = cum;
        cum += csz[s] / 8;
    }
    ca.cum[14] = cum;

    // mega: in-proj GEMM (blocks 0..511, x & inp_w both f32) + convert rest
    // (blocks 512..2559, incl. rtab + inp_b in block 512). No prologue.
    inproj_conv<<<2560, 256, 0, stream>>>(
        (const float*)d_in[0], (const float*)d_in[1], skpart, ca, cum,
        (const float*)d_in[2], wts + O_INPB, rtab);
    sk_reduce<8><<<1024, 256, 0, stream>>>(skpart, wts + O_INPB, h);

    for (int i = 0; i < 6; ++i) {
        const __hip_bfloat16* wqkv = wts + O_INPROJ + (long)i * 1536 * 512;
        const __hip_bfloat16* bqkv = wts + O_INPROJB + i * 1536;

        // fused rope(q,k) | identity(v): 64x128 reg-staged, 384 blocks
        gemm_bt<64, 128, 0, 0><<<dim3(32, 12), 256, 0, stream>>>(
            h, 8, rtab, wqkv, bqkv, qkv, M, 1536, 512, 512);
        attn_mfma<<<128, 256, 0, stream>>>(qkv, ctx);
        // out-proj: split-K z=2 -> f32 partials (512 blocks), 64x64 reg-staged
        gemm_bt<64, 64, 0, 1><<<dim3(32, 8, 2), 256, 0, stream>>>(
            ctx, 0, rtab, wts + O_OUTW + (long)i * 512 * 512, wts + O_OUTB + i * 512,
            skpart, M, 512, 512, 256);
        // ht = LN1(h + (sum partials + out_b))
        skred_add_ln<2><<<512, 256, 0, stream>>>(
            skpart, wts + O_OUTB + i * 512, h,
            wts + O_LN1W + i * 512, wts + O_LN1B + i * 512, ht);
        // ff1 + gelu: 64x128 reg-staged, 512 blocks
        gemm_bt<64, 128, 1, 0><<<dim3(32, 16), 256, 0, stream>>>(
            ht, 0, rtab, wts + O_FF1 + (long)i * 2048 * 512, wts + O_FF1B + i * 2048,
            ffh, M, 2048, 512, 512);
        // ff2: split-K z=4 -> f32 partials, 64x128 reg-staged (512 blocks)
        gemm_bt<64, 128, 0, 1><<<dim3(32, 4, 4), 256, 0, stream>>>(
            ffh, 0, rtab, wts + O_FF2 + (long)i * 512 * 2048, wts + O_FF2B + i * 512,
            skpart, M, 512, 2048, 512);
        // h = LN2(ht + (sum partials + ff2_b))
        skred_add_ln<4><<<512, 256, 0, stream>>>(
            skpart, wts + O_FF2B + i * 512, ht,
            wts + O_LN2W + i * 512, wts + O_LN2B + i * 512, h);
    }

    // output projection: f32 out, 128x128 reg-staged, 1152 blocks
    gemm_bt<128, 128, 0, 2><<<dim3(16, 72), 256, 0, stream>>>(
        h, 0, rtab, wts + O_OUTPW, wts + O_OUTPB, d_out, M, 9216, 512, 512);
}

// Round 21
// 458.170 us; speedup vs baseline: 1.0396x; 1.0396x over previous
//
#include <hip/hip_runtime.h>
#include <hip/hip_bf16.h>
#include <math.h>

// DiT flow: B=64,S=32 -> M=2048 tokens, D=512, NH=8, HD=64, FF=2048, L=6, IN=9216.
// Device buffers are FLOAT32. Compute: bf16 MFMA, f32 accumulation; weights
// pre-converted to bf16 in ws each call (deterministic).
// NOTE (r16): no runtime-indexed register staging arrays (rule #20 scratch).
// r21 = exact reproduction of the best measured configuration (r18, 458 us).

typedef __attribute__((ext_vector_type(8))) short bf16x8;
typedef __attribute__((ext_vector_type(4))) short bf16x4;
typedef __attribute__((ext_vector_type(8))) float f32x8;
typedef __attribute__((ext_vector_type(4))) float f32x4;

#define LN_EPS 1e-5f

__device__ inline float bf2f(__hip_bfloat16 v) { return __bfloat162float(v); }
__device__ inline __hip_bfloat16 f2bf(float f) { return __float2bfloat16(f); }

__device__ __forceinline__ void gload_lds16(const __hip_bfloat16* g, __hip_bfloat16* l) {
    __builtin_amdgcn_global_load_lds(
        (const __attribute__((address_space(1))) unsigned*)g,
        (__attribute__((address_space(3))) unsigned*)l, 16, 0, 0);
}

__device__ __forceinline__ void sync_tile() {
    asm volatile("s_waitcnt vmcnt(0) lgkmcnt(0)" ::: "memory");
    __builtin_amdgcn_s_barrier();
    asm volatile("" ::: "memory");
}

__device__ __forceinline__ void sync_lds() {   // no vmem drain — reg-staged paths
    asm volatile("s_waitcnt lgkmcnt(0)" ::: "memory");
    __builtin_amdgcn_s_barrier();
    asm volatile("" ::: "memory");
}

// ---------------------------------------------------------------------------
// Convert f32 -> bf16 (coalesced per-8-chunk grid-stride, 2-way unrolled) +
// rope table fill (block 0).
// ---------------------------------------------------------------------------
struct CvtSeg { const float* src; __hip_bfloat16* dst; };
struct CvtArgs { CvtSeg seg[16]; long cum[17]; };

__global__ __launch_bounds__(256) void convert_all(CvtArgs a, long total8,
                                                   float* __restrict__ rtab) {
    if (blockIdx.x == 0) {
#pragma unroll
        for (int it = 0; it < 4; ++it) {
            const int t = it * 256 + threadIdx.x;
            const int s = t >> 5, p = t & 31;
            const float theta = powf(10000.f, -(float)p / 32.f);
            float sn, cs;
            sincosf((float)s * theta, &sn, &cs);
            rtab[t * 2] = cs;
            rtab[t * 2 + 1] = sn;
        }
    }
    const long st = (long)gridDim.x * 256;
    for (long i = (long)blockIdx.x * 256 + threadIdx.x; i < total8; i += 2 * st) {
        int s1 = 0;
        while (i >= a.cum[s1 + 1]) ++s1;
        const long o1 = i - a.cum[s1];
        const f32x8 x1 = *((const f32x8*)a.seg[s1].src + o1);

        const long j = i + st;
        if (j < total8) {
            int s2 = s1;
            while (j >= a.cum[s2 + 1]) ++s2;
            const long o2 = j - a.cum[s2];
            const f32x8 x2 = *((const f32x8*)a.seg[s2].src + o2);

            union { bf16x8 v; __hip_bfloat16 b[8]; } u1, u2;
#pragma unroll
            for (int t = 0; t < 8; ++t) { u1.b[t] = f2bf(x1[t]); u2.b[t] = f2bf(x2[t]); }
            *((bf16x8*)a.seg[s1].dst + o1) = u1.v;
            *((bf16x8*)a.seg[s2].dst + o2) = u2.v;
        } else {
            union { bf16x8 v; __hip_bfloat16 b[8]; } u1;
#pragma unroll
            for (int t = 0; t < 8; ++t) u1.b[t] = f2bf(x1[t]);
            *((bf16x8*)a.seg[s1].dst + o1) = u1.v;
        }
    }
}

// ---------------------------------------------------------------------------
// GEMM: C[M,N] = A[M,K] @ W[N,K]^T (+bias, +gelu). Tile BM x BN, BK=64,
// 4 waves 2x2 (per-wave (BM/2)x(BN/2)). XOR-swizzled LDS rows (involution).
// PIPE: 0 = single-buffer m97 2-barrier loop; 1 = 2-phase double-buffer.
// AMODE: 0 = A bf16 gload_lds; 1 = A f32 reg-staged; 2 = A bf16 reg-staged +
//        rope; 3 = A f32 + B bf16 reg-staged, lgkm-only sync (no vmem drain);
//        4 = A bf16 (rope for bn < bn_split) + B bf16 reg-staged, lgkm-only.
// OUT:   0 = bf16 +bias(+EPI gelu); 1 = f32 split-K partial; 2 = f32 +bias.
// SWZ:   0 = m204 XCD swizzle; 1 = A-panel-grouped per XCD (1D grid).
// ---------------------------------------------------------------------------
template<int BM, int BN, int EPI, int OUT, int AMODE, int SWZ, int PIPE>
__global__ __launch_bounds__(256) void gemm_bt(
    const void* __restrict__ Araw, int bn_split,
    const float* __restrict__ rtab,
    const __hip_bfloat16* __restrict__ W,
    const __hip_bfloat16* __restrict__ bias,
    void* __restrict__ Cv,
    int M, int N, int Ktot, int KC)
{
    constexpr int FM = BM / 32, FN = BN / 32;
    constexpr int CPT_A = BM / 32, CPT_B = BN / 32;
    constexpr bool REGSTAGE = (AMODE == 3 || AMODE == 4);
    constexpr int NBUF = (PIPE && !REGSTAGE) ? 2 : 1;
    __shared__ __align__(16) __hip_bfloat16 sA[NBUF][BM * 64];
    __shared__ __align__(16) __hip_bfloat16 sB[NBUF][BN * 64];

    const int tid = threadIdx.x, lane = tid & 63, wave = tid >> 6;
    const int wr = wave >> 1, wc = wave & 1;
    const int lr = lane & 15, lk = lane >> 4;

    int bm, bn, zz;
    if (SWZ == 0) {
        const int nbm = gridDim.x, nbn = gridDim.y;
        const int nwg = nbm * nbn;
        const int orig = blockIdx.y * nbm + blockIdx.x;
        const int q8 = nwg >> 3, r8 = nwg & 7;
        const int xcd = orig & 7, loc = orig >> 3;
        const int f = (xcd < r8 ? xcd * (q8 + 1) : r8 * (q8 + 1) + (xcd - r8) * q8) + loc;
        bm = f % nbm; bn = f / nbm; zz = blockIdx.z;
    } else {
        const int bid = blockIdx.x;
        const int xcd = bid & 7, loc = bid >> 3;
        const int nbn = N / BN;
        const int per = (gridDim.x >> 3) / nbn;
        bn = loc % nbn;
        const int gid = xcd * per + loc / nbn;
        bm = gid % (M / BM); zz = gid / (M / BM);
    }
    const int kbeg = zz * KC, kend = kbeg + KC;
    const bool dorot = (AMODE == 2 || AMODE == 4) && (bn < bn_split);

    const __hip_bfloat16* Ab = (const __hip_bfloat16*)Araw + (long)bm * BM * Ktot;
    const float*          Af = (const float*)Araw + (long)bm * BM * Ktot;
    const __hip_bfloat16* Wb = W + (long)bn * BN * Ktot;

    f32x4 acc[FM][FN];
#pragma unroll
    for (int i = 0; i < FM; ++i)
#pragma unroll
        for (int j = 0; j < FN; ++j) acc[i][j] = (f32x4){0.f, 0.f, 0.f, 0.f};

    f32x8  aregf[CPT_A];
    bf16x8 aregb[CPT_A];
    f32x8  csreg[CPT_A];
    bf16x8 bregb[REGSTAGE ? CPT_B : 1];

    auto stageA_g = [&](int buf, int k0) {
#pragma unroll
        for (int c = 0; c < CPT_A; ++c) {
            const int ch = tid + c * 256, row = ch >> 3, co = ch & 7;
            gload_lds16(&Ab[(long)row * Ktot + k0 + ((co ^ (row & 7)) * 8)],
                        (__hip_bfloat16*)((char*)&sA[buf][0] + ch * 16));
        }
    };
    auto stageB_g = [&](int buf, int k0) {
#pragma unroll
        for (int c = 0; c < CPT_B; ++c) {
            const int ch = tid + c * 256, row = ch >> 3, co = ch & 7;
            gload_lds16(&Wb[(long)row * Ktot + k0 + ((co ^ (row & 7)) * 8)],
                        (__hip_bfloat16*)((char*)&sB[buf][0] + ch * 16));
        }
    };
    auto issueA = [&](int k0) {
#pragma unroll
        for (int c = 0; c < CPT_A; ++c) {
            const int ch = tid + c * 256, row = ch >> 3, co = ch & 7;
            if (AMODE == 1 || AMODE == 3)
                aregf[c] = *(const f32x8*)&Af[(long)row * Ktot + k0 + co * 8];
            if (AMODE == 2 || AMODE == 4) {
                aregb[c] = *(const bf16x8*)&Ab[(long)row * Ktot + k0 + co * 8];
                if (dorot)
                    csreg[c] = *(const f32x8*)&rtab[((bm * BM + row) & 31) * 64 + co * 8];
            }
        }
        if (REGSTAGE) {
#pragma unroll
            for (int c = 0; c < CPT_B; ++c) {
                const int ch = tid + c * 256, row = ch >> 3, co = ch & 7;
                bregb[c] = *(const bf16x8*)&Wb[(long)row * Ktot + k0 + co * 8];
            }
        }
    };
    auto writeA = [&](int buf) {
#pragma unroll
        for (int c = 0; c < CPT_A; ++c) {
            const int ch = tid + c * 256, row = ch >> 3, co = ch & 7;
            union { bf16x8 v; __hip_bfloat16 b[8]; } t;
            if (AMODE == 1 || AMODE == 3) {
#pragma unroll
                for (int j = 0; j < 8; ++j) t.b[j] = f2bf(aregf[c][j]);
            } else {
                t.v = aregb[c];
                if (dorot) {
#pragma unroll
                    for (int qd = 0; qd < 4; ++qd) {
                        const float c_ = csreg[c][qd * 2], sn = csreg[c][qd * 2 + 1];
                        const float x0 = bf2f(t.b[2 * qd]);
                        const float x1 = bf2f(t.b[2 * qd + 1]);
                        t.b[2 * qd]     = f2bf(x0 * c_ - x1 * sn);
                        t.b[2 * qd + 1] = f2bf(x1 * c_ + x0 * sn);
                    }
                }
            }
            *(bf16x8*)((char*)&sA[buf][0] + row * 128 + ((co ^ (row & 7)) << 4)) = t.v;
        }
        if (REGSTAGE) {
#pragma unroll
            for (int c = 0; c < CPT_B; ++c) {
                const int ch = tid + c * 256, row = ch >> 3, co = ch & 7;
                *(bf16x8*)((char*)&sB[buf][0] + row * 128 + ((co ^ (row & 7)) << 4)) = bregb[c];
            }
        }
    };
    auto compute = [&](int buf) {
        bf16x8 af[2][FM], bfr[2][FN];
#pragma unroll
        for (int ks = 0; ks < 2; ++ks) {
#pragma unroll
            for (int i = 0; i < FM; ++i) {
                const int row = wr * (BM / 2) + i * 16 + lr;
                const int co = ks * 4 + lk;
                af[ks][i] = *(const bf16x8*)((const char*)&sA[buf][0] + row * 128 +
                                             ((co ^ (row & 7)) << 4));
            }
#pragma unroll
            for (int j = 0; j < FN; ++j) {
                const int row = wc * (BN / 2) + j * 16 + lr;
                const int co = ks * 4 + lk;
                bfr[ks][j] = *(const bf16x8*)((const char*)&sB[buf][0] + row * 128 +
                                              ((co ^ (row & 7)) << 4));
            }
        }
#pragma unroll
        for (int ks = 0; ks < 2; ++ks)
#pragma unroll
            for (int i = 0; i < FM; ++i)
#pragma unroll
                for (int j = 0; j < FN; ++j)
                    acc[i][j] = __builtin_amdgcn_mfma_f32_16x16x32_bf16(
                        af[ks][i], bfr[ks][j], acc[i][j], 0, 0, 0);
    };

    if (REGSTAGE) {
        issueA(kbeg);
        for (int k0 = kbeg; k0 < kend; k0 += 64) {
            if (k0 > kbeg) __builtin_amdgcn_s_barrier();
            writeA(0);
            sync_lds();
            if (k0 + 64 < kend) issueA(k0 + 64);
            compute(0);
        }
    } else if (PIPE == 0) {
        if (AMODE != 0) issueA(kbeg);
        for (int k0 = kbeg; k0 < kend; k0 += 64) {
            if (k0 > kbeg) __builtin_amdgcn_s_barrier();
            if (AMODE == 0) stageA_g(0, k0);
            stageB_g(0, k0);
            if (AMODE != 0) writeA(0);
            sync_tile();
            if (AMODE != 0 && k0 + 64 < kend) issueA(k0 + 64);
            compute(0);
        }
    } else {
        if (AMODE == 0) stageA_g(0, kbeg); else issueA(kbeg);
        stageB_g(0, kbeg);
        if (AMODE != 0) writeA(0);
        sync_tile();
        int cur = 0;
        for (int k0 = kbeg; k0 < kend; k0 += 64) {
            const bool hn = (k0 + 64 < kend);
            if (hn) {
                if (AMODE == 0) stageA_g(cur ^ 1, k0 + 64); else issueA(k0 + 64);
                stageB_g(cur ^ 1, k0 + 64);
            }
            compute(cur);
            if (hn) {
                if (AMODE != 0) writeA(cur ^ 1);
                sync_tile();
            }
            cur ^= 1;
        }
    }

    const int row0 = bm * BM + wr * (BM / 2);
    const int col0 = bn * BN + wc * (BN / 2);
    if (OUT == 1) {
        float* Cp = (float*)Cv + (long)zz * M * N;
#pragma unroll
        for (int i = 0; i < FM; ++i)
#pragma unroll
            for (int j = 0; j < FN; ++j) {
                const int col = col0 + j * 16 + lr;
#pragma unroll
                for (int r = 0; r < 4; ++r)
                    Cp[(long)(row0 + i * 16 + lk * 4 + r) * N + col] = acc[i][j][r];
            }
    } else {
#pragma unroll
        for (int i = 0; i < FM; ++i)
#pragma unroll
            for (int j = 0; j < FN; ++j) {
                const int col = col0 + j * 16 + lr;
                const float bv = bf2f(bias[col]);
#pragma unroll
                for (int r = 0; r < 4; ++r) {
                    const int row = row0 + i * 16 + lk * 4 + r;
                    float v = acc[i][j][r] + bv;
                    if (EPI == 1) v = 0.5f * v * (1.0f + erff(v * 0.70710678118654752f));
                    const long idx = (long)row * N + col;
                    if (OUT == 2) ((float*)Cv)[idx] = v;
                    else          ((__hip_bfloat16*)Cv)[idx] = f2bf(v);
                }
            }
    }
}

// ---------------------------------------------------------------------------
template<int SK>
__global__ __launch_bounds__(256) void sk_reduce(
    const float* __restrict__ part, const __hip_bfloat16* __restrict__ bias,
    __hip_bfloat16* __restrict__ out)
{
    const long MN = 2048L * 512;
    const long i4 = ((long)blockIdx.x * 256 + threadIdx.x) * 4;
    f32x4 s = (f32x4){0.f, 0.f, 0.f, 0.f};
#pragma unroll
    for (int z = 0; z < SK; ++z) s += *(const f32x4*)&part[z * MN + i4];
    const int col = (int)(i4 & 511);
    union { bf16x4 v; __hip_bfloat16 b[4]; } o;
#pragma unroll
    for (int j = 0; j < 4; ++j) o.b[j] = f2bf(s[j] + bf2f(bias[col + j]));
    *(bf16x4*)&out[i4] = o.v;
}

// ---------------------------------------------------------------------------
// Fused split-K reduce + bias + residual add + LayerNorm (D=512).
// ---------------------------------------------------------------------------
template<int SK>
__global__ __launch_bounds__(256) void skred_add_ln(
    const float* __restrict__ part, const __hip_bfloat16* __restrict__ bias,
    const __hip_bfloat16* __restrict__ resid,
    const __hip_bfloat16* __restrict__ w, const __hip_bfloat16* __restrict__ b,
    __hip_bfloat16* __restrict__ out)
{
    const long MN = 2048L * 512;
    const int wave = threadIdx.x >> 6, lane = threadIdx.x & 63;
    const long row = (long)blockIdx.x * 4 + wave;
    const long base = row * 512 + lane * 8;

    f32x8 acc = *(const f32x8*)&part[base];
#pragma unroll
    for (int z = 1; z < SK; ++z) acc += *(const f32x8*)&part[z * MN + base];

    union { bf16x8 v; __hip_bfloat16 b[8]; } ur, uo;
    ur.v = *(const bf16x8*)&resid[base];

    float x[8];
    float s = 0.f, s2 = 0.f;
#pragma unroll
    for (int j = 0; j < 8; ++j) {
        const int col = lane * 8 + j;
        x[j] = acc[j] + bf2f(bias[col]) + bf2f(ur.b[j]);
        s += x[j];
        s2 += x[j] * x[j];
    }
#pragma unroll
    for (int off = 32; off; off >>= 1) {
        s  += __shfl_xor(s, off);
        s2 += __shfl_xor(s2, off);
    }
    const float mu = s * (1.f / 512.f);
    const float var = s2 * (1.f / 512.f) - mu * mu;
    const float rs = rsqrtf(var + LN_EPS);
#pragma unroll
    for (int j = 0; j < 8; ++j) {
        const int col = lane * 8 + j;
        uo.b[j] = f2bf((x[j] - mu) * rs * bf2f(w[col]) + bf2f(b[col]));
    }
    *(bf16x8*)&out[base] = uo.v;
}

// ---------------------------------------------------------------------------
// MFMA attention: one wave per (b,head); 4 waves/block, 128 blocks.
// ---------------------------------------------------------------------------
__global__ __launch_bounds__(256) void attn_mfma(
    const __hip_bfloat16* __restrict__ qkv, __hip_bfloat16* __restrict__ ctx)
{
    __shared__ __align__(16) __hip_bfloat16 sP[4][32 * 32];
    __shared__ __align__(16) __hip_bfloat16 sVT[4][64 * 32];

    const int wave = threadIdx.x >> 6, lane = threadIdx.x & 63;
    const int bh = blockIdx.x * 4 + wave;
    const int b = bh >> 3, head = bh & 7;
    const long tok0 = (long)b * 32;
    const int lr = lane & 15, lk = lane >> 4;

    const __hip_bfloat16* Qb = qkv + tok0 * 1536 + head * 64;
    const __hip_bfloat16* Kb = Qb + 512;
    const __hip_bfloat16* Vb = Qb + 1024;

#pragma unroll
    for (int t = 0; t < 4; ++t) {
        const int c = lane + t * 64, row = c >> 3, d0 = (c & 7) * 8;
        union { bf16x8 v; __hip_bfloat16 e[8]; } u;
        u.v = *(const bf16x8*)&Vb[(long)row * 1536 + d0];
#pragma unroll
        for (int e = 0; e < 8; ++e) sVT[wave][(d0 + e) * 32 + row] = u.e[e];
    }

    f32x4 sc[2][2];
#pragma unroll
    for (int i = 0; i < 2; ++i)
#pragma unroll
        for (int j = 0; j < 2; ++j) sc[i][j] = (f32x4){0.f, 0.f, 0.f, 0.f};
#pragma unroll
    for (int ks = 0; ks < 2; ++ks) {
        bf16x8 aq[2], bk[2];
#pragma unroll
        for (int i = 0; i < 2; ++i)
            aq[i] = *(const bf16x8*)&Qb[(long)(i * 16 + lr) * 1536 + ks * 32 + lk * 8];
#pragma unroll
        for (int j = 0; j < 2; ++j)
            bk[j] = *(const bf16x8*)&Kb[(long)(j * 16 + lr) * 1536 + ks * 32 + lk * 8];
#pragma unroll
        for (int i = 0; i < 2; ++i)
#pragma unroll
            for (int j = 0; j < 2; ++j)
                sc[i][j] = __builtin_amdgcn_mfma_f32_16x16x32_bf16(aq[i], bk[j], sc[i][j], 0, 0, 0);
    }

    float p[2][2][4], inv[2][4];
#pragma unroll
    for (int i = 0; i < 2; ++i) {
#pragma unroll
        for (int r = 0; r < 4; ++r) {
            const int row = i * 16 + lk * 4 + r;
            float m = -3.0e38f;
#pragma unroll
            for (int j = 0; j < 2; ++j) {
                const int col = j * 16 + lr;
                const float v = (col <= row) ? sc[i][j][r] * 0.125f : -3.0e38f;
                p[i][j][r] = v;
                m = fmaxf(m, v);
            }
#pragma unroll
            for (int off = 1; off < 16; off <<= 1)
                m = fmaxf(m, __shfl_xor(m, off));
            float l = 0.f;
#pragma unroll
            for (int j = 0; j < 2; ++j) {
                p[i][j][r] = expf(p[i][j][r] - m);
                l += p[i][j][r];
            }
#pragma unroll
            for (int off = 1; off < 16; off <<= 1)
                l += __shfl_xor(l, off);
            inv[i][r] = 1.f / l;
        }
    }

#pragma unroll
    for (int i = 0; i < 2; ++i)
#pragma unroll
        for (int j = 0; j < 2; ++j)
#pragma unroll
            for (int r = 0; r < 4; ++r)
                sP[wave][(i * 16 + lk * 4 + r) * 32 + j * 16 + lr] = f2bf(p[i][j][r]);

    bf16x8 pa[2], vb[4];
#pragma unroll
    for (int i = 0; i < 2; ++i)
        pa[i] = *(const bf16x8*)&sP[wave][(i * 16 + lr) * 32 + lk * 8];
#pragma unroll
    for (int j = 0; j < 4; ++j)
        vb[j] = *(const bf16x8*)&sVT[wave][(j * 16 + lr) * 32 + lk * 8];

    f32x4 o[2][4];
#pragma unroll
    for (int i = 0; i < 2; ++i)
#pragma unroll
        for (int j = 0; j < 4; ++j) {
            o[i][j] = (f32x4){0.f, 0.f, 0.f, 0.f};
            o[i][j] = __builtin_amdgcn_mfma_f32_16x16x32_bf16(pa[i], vb[j], o[i][j], 0, 0, 0);
        }

#pragma unroll
    for (int i = 0; i < 2; ++i)
#pragma unroll
        for (int j = 0; j < 4; ++j) {
            const int col = j * 16 + lr;
#pragma unroll
            for (int r = 0; r < 4; ++r) {
                const int row = i * 16 + lk * 4 + r;
                ctx[(tok0 + row) * 512 + head * 64 + col] = f2bf(o[i][j][r] * inv[i][r]);
            }
        }
}

// ---------------------------------------------------------------------------
extern "C" void kernel_launch(void* const* d_in, const int* in_sizes, int n_in,
                              void* d_out, int out_size, void* d_ws, size_t ws_size,
                              hipStream_t stream)
{
    const int M = 2048;
    __hip_bfloat16* wts = (__hip_bfloat16*)d_ws;

    const long O_INPW   = 0;          // 4718592
    const long O_INPROJ = 4718592;    // 4718592
    const long O_OUTW   = 9437184;    // 1572864
    const long O_FF1    = 11010048;   // 6291456
    const long O_FF2    = 17301504;   // 6291456
    const long O_OUTPW  = 23592960;   // 4718592
    const long O_INPB   = 28311552;   // 512
    const long O_INPROJB= 28312064;   // 9216
    const long O_OUTB   = 28321280;   // 3072
    const long O_LN1W   = 28324352;   // 3072
    const long O_LN1B   = 28327424;   // 3072
    const long O_LN2W   = 28330496;   // 3072
    const long O_LN2B   = 28333568;   // 3072
    const long O_FF1B   = 28336640;   // 12288
    const long O_FF2B   = 28348928;   // 3072
    const long O_OUTPB  = 28352000;   // 9216
    const long O_ACT    = 28361216;

    __hip_bfloat16* h   = wts + O_ACT;                   // [M,512]
    __hip_bfloat16* ht  = h   + (long)M * 512;
    __hip_bfloat16* qkv = ht  + (long)M * 512;           // [M,1536]
    __hip_bfloat16* ctx = qkv + (long)M * 1536;
    __hip_bfloat16* ffh = ctx + (long)M * 512;           // [M,2048]
    float* rtab = (float*)(ffh + (long)M * 2048);        // 8 KB
    float* skpart = (float*)((__hip_bfloat16*)rtab + 4096);  // 8 x 4.2 MB f32

    const int  cidx[16] = {1, 3, 5, 11, 13, 15, 2, 4, 6, 7, 8, 9, 10, 12, 14, 16};
    const long coff[16] = {O_INPW, O_INPROJ, O_OUTW, O_FF1, O_FF2, O_OUTPW,
                           O_INPB, O_INPROJB, O_OUTB, O_LN1W, O_LN1B, O_LN2W,
                           O_LN2B, O_FF1B, O_FF2B, O_OUTPB};
    const long csz[16]  = {4718592, 4718592, 1572864, 6291456, 6291456, 4718592,
                           512, 9216, 3072, 3072, 3072, 3072, 3072, 12288, 3072, 9216};
    CvtArgs ca;
    long cum = 0;
    for (int s = 0; s < 16; ++s) {
        ca.seg[s].src = (const float*)d_in[cidx[s]];
        ca.seg[s].dst = wts + coff[s];
        ca.cum[s] = cum;
        cum += csz[s] / 8;
    }
    ca.cum[16] = cum;
    convert_all<<<2048, 256, 0, stream>>>(ca, cum, rtab);

    // input projection from raw f32 x: 64x256 tiles, z=8, 512 blocks, fully
    // reg-staged A+B (AMODE=3): no vmem drain in the K-loop.
    gemm_bt<64, 256, 0, 1, 3, 1, 0><<<512, 256, 0, stream>>>(
        d_in[0], 0, rtab, wts + O_INPW, wts + O_INPB, skpart, M, 512, 9216, 1152);
    sk_reduce<8><<<1024, 256, 0, stream>>>(skpart, wts + O_INPB, h);

    for (int i = 0; i < 6; ++i) {
        const __hip_bfloat16* wqkv = wts + O_INPROJ + (long)i * 1536 * 512;
        const __hip_bfloat16* bqkv = wts + O_INPROJB + i * 1536;

        // fused rope(q,k) | identity(v): 64x128 reg-staged, 384 blocks
        // (per-wave 32x64: 16 MFMA / 12 ds_read per K-step)
        gemm_bt<64, 128, 0, 0, 4, 0, 0><<<dim3(32, 12), 256, 0, stream>>>(
            h, 8, rtab, wqkv, bqkv, qkv, M, 1536, 512, 512);
        attn_mfma<<<128, 256, 0, stream>>>(qkv, ctx);
        // out-proj: split-K z=2 -> f32 partials (512 blocks), 64x64 reg-staged
        gemm_bt<64, 64, 0, 1, 4, 0, 0><<<dim3(32, 8, 2), 256, 0, stream>>>(
            ctx, 0, rtab, wts + O_OUTW + (long)i * 512 * 512, wts + O_OUTB + i * 512,
            skpart, M, 512, 512, 256);
        // ht = LN1(h + (sum partials + out_b))
        skred_add_ln<2><<<512, 256, 0, stream>>>(
            skpart, wts + O_OUTB + i * 512, h,
            wts + O_LN1W + i * 512, wts + O_LN1B + i * 512, ht);
        // ff1 + gelu: 64x128 reg-staged, 512 blocks
        gemm_bt<64, 128, 1, 0, 4, 0, 0><<<dim3(32, 16), 256, 0, stream>>>(
            ht, 0, rtab, wts + O_FF1 + (long)i * 2048 * 512, wts + O_FF1B + i * 2048,
            ffh, M, 2048, 512, 512);
        // ff2: split-K z=4 -> f32 partials, 64x128 reg-staged (512 blocks)
        gemm_bt<64, 128, 0, 1, 4, 0, 0><<<dim3(32, 4, 4), 256, 0, stream>>>(
            ffh, 0, rtab, wts + O_FF2 + (long)i * 512 * 2048, wts + O_FF2B + i * 512,
            skpart, M, 512, 2048, 512);
        // h = LN2(ht + (sum partials + ff2_b))
        skred_add_ln<4><<<512, 256, 0, stream>>>(
            skpart, wts + O_FF2B + i * 512, ht,
            wts + O_LN2W + i * 512, wts + O_LN2B + i * 512, h);
    }

    // output projection: f32 out, 128x128 reg-staged, 1152 blocks
    gemm_bt<128, 128, 0, 2, 4, 0, 0><<<dim3(16, 72), 256, 0, stream>>>(
        h, 0, rtab, wts + O_OUTPW, wts + O_OUTPB, d_out, M, 9216, 512, 512);
}